// Round 1
// baseline (200.625 us; speedup 1.0000x reference)
//
#include <hip/hip_runtime.h>
#include <hip/hip_bf16.h>

#define B_ 32
#define S_ 4096
#define H_ 512

typedef short bf16x8 __attribute__((ext_vector_type(8)));
typedef float f32x4 __attribute__((ext_vector_type(4)));

__device__ inline unsigned short f2bf(float x) {
    unsigned u = __float_as_uint(x);
    return (unsigned short)((u + 0x7fffu + ((u >> 16) & 1u)) >> 16);
}

__device__ inline float fast_tanh(float x) {
    float e = __expf(2.f * x);
    return 1.f - 2.f / (e + 1.f);
}

// ---------------------------------------------------------------------------
// Kernel 1: transpose+convert Ua[h][d] (f32) -> ua_tiled[kk][d][c] (bf16)
//   ua_tiled[(kk*512 + d)*32 + c] = bf16(Ua[(kk*32 + c)*512 + d])
// so the GEMM's B-tile staging reads 64B-contiguous, line-dense rows.
// grid (16,16), block (32,8)
// ---------------------------------------------------------------------------
__global__ void k_prep_ua(const float* __restrict__ Ua,
                          unsigned short* __restrict__ ua_tiled) {
    __shared__ float tile[32][33];
    int h0 = blockIdx.x * 32, d0 = blockIdx.y * 32;
    int tx = threadIdx.x, ty = threadIdx.y;
#pragma unroll
    for (int j = 0; j < 4; ++j)
        tile[ty + j * 8][tx] = Ua[(size_t)(h0 + ty + j * 8) * H_ + d0 + tx];
    __syncthreads();
#pragma unroll
    for (int j = 0; j < 4; ++j) {
        int dd = ty + j * 8;
        ua_tiled[((size_t)blockIdx.x * H_ + d0 + dd) * 32 + tx] = f2bf(tile[tx][dd]);
    }
}

// ---------------------------------------------------------------------------
// Kernel 2: q_proj[b][d] = sum_h query[b][h] * Wa[h][d]   (fp32, tiny)
// grid (32), block (512)
// ---------------------------------------------------------------------------
__global__ __launch_bounds__(512) void k_qproj(const float* __restrict__ query,
                                               const float* __restrict__ Wa,
                                               float* __restrict__ qproj) {
    __shared__ float q[H_];
    int b = blockIdx.x, d = threadIdx.x;
    q[d] = query[(size_t)b * H_ + d];
    __syncthreads();
    float acc = 0.f;
    for (int h = 0; h < H_; ++h)
        acc = fmaf(q[h], Wa[(size_t)h * H_ + d], acc);
    qproj[(size_t)b * H_ + d] = acc;
}

// ---------------------------------------------------------------------------
// Kernel 3: scores[b][s] = sum_d Va[d]*tanh(qproj[b][d] + (keys[b]·Ua)[s][d])
// MFMA bf16 GEMM: block tile 64(M) x 512(N=full H), BK=32, 512 threads,
// 8 waves each owning a 64x64 output (4x4 frags of 16x16x32).
// grid (64, 32) = (m-tiles, batch)
// ---------------------------------------------------------------------------
#define BM  64
#define BK  32
#define LDT 40   // padded LDS row (elements); 80 B = 5*16 B -> b128-aligned, 2-way banks (free)

__global__ __launch_bounds__(512) void k_scores(
    const float* __restrict__ keys, const unsigned short* __restrict__ ua_tiled,
    const float* __restrict__ qproj, const float* __restrict__ Va,
    float* __restrict__ scores) {
    __shared__ unsigned short As[BM * LDT];
    __shared__ unsigned short Bs[H_ * LDT];
    __shared__ float sm_part[8][BM];

    int tid = threadIdx.x;
    int wave = tid >> 6, lane = tid & 63;
    int wn = wave;                // 8 waves tile N
    int lq = lane & 15, lh = lane >> 4;
    int b = blockIdx.y;
    int m0 = blockIdx.x * BM;

    const float* keysb = keys + (size_t)b * S_ * H_;

    f32x4 acc[4][4];
#pragma unroll
    for (int i = 0; i < 4; ++i)
#pragma unroll
        for (int j = 0; j < 4; ++j) acc[i][j] = (f32x4){0.f, 0.f, 0.f, 0.f};

    // staging maps
    int ar = tid >> 3, ac4 = (tid & 7) << 2;                 // A: 64 rows x 32 cols, float4/thread
    const float* aptr = keysb + (size_t)(m0 + ar) * H_ + ac4;
    const unsigned short* bptr = ua_tiled + (size_t)tid * 32; // B: one 32-elem row per thread

    for (int kk = 0; kk < H_ / BK; ++kk) {
        int k0 = kk * BK;
        // issue global loads before the barrier (overlap with prior compute)
        float4 av = *(const float4*)(aptr + k0);
        const unsigned short* bsrc = bptr + (size_t)kk * H_ * 32;
        uint4 bv0 = *(const uint4*)(bsrc + 0);
        uint4 bv1 = *(const uint4*)(bsrc + 8);
        uint4 bv2 = *(const uint4*)(bsrc + 16);
        uint4 bv3 = *(const uint4*)(bsrc + 24);
        __syncthreads();   // previous iteration's frag reads complete
        ushort4 aw;
        aw.x = f2bf(av.x); aw.y = f2bf(av.y); aw.z = f2bf(av.z); aw.w = f2bf(av.w);
        *(ushort4*)&As[ar * LDT + ac4] = aw;
        *(uint4*)&Bs[tid * LDT + 0]  = bv0;
        *(uint4*)&Bs[tid * LDT + 8]  = bv1;
        *(uint4*)&Bs[tid * LDT + 16] = bv2;
        *(uint4*)&Bs[tid * LDT + 24] = bv3;
        __syncthreads();

        bf16x8 af[4], bfr[4];
#pragma unroll
        for (int mf = 0; mf < 4; ++mf)
            af[mf] = *(const bf16x8*)&As[(mf * 16 + lq) * LDT + lh * 8];
#pragma unroll
        for (int nf = 0; nf < 4; ++nf)
            bfr[nf] = *(const bf16x8*)&Bs[(wn * 64 + nf * 16 + lq) * LDT + lh * 8];
#pragma unroll
        for (int mf = 0; mf < 4; ++mf)
#pragma unroll
            for (int nf = 0; nf < 4; ++nf)
                acc[mf][nf] = __builtin_amdgcn_mfma_f32_16x16x32_bf16(
                    af[mf], bfr[nf], acc[mf][nf], 0, 0, 0);
    }

    // epilogue: score partial = sum_n Va[n]*tanh(qp[n] + C[m,n])
    float va_r[4], qp_r[4];
#pragma unroll
    for (int nf = 0; nf < 4; ++nf) {
        int n = wn * 64 + nf * 16 + lq;
        va_r[nf] = Va[n];
        qp_r[nf] = qproj[(size_t)b * H_ + n];
    }
#pragma unroll
    for (int mf = 0; mf < 4; ++mf) {
#pragma unroll
        for (int reg = 0; reg < 4; ++reg) {
            float p = 0.f;
#pragma unroll
            for (int nf = 0; nf < 4; ++nf)
                p += va_r[nf] * fast_tanh(qp_r[nf] + acc[mf][nf][reg]);
            // reduce across the 16 lanes sharing this output row (lane bits 0..3)
            p += __shfl_xor(p, 1);
            p += __shfl_xor(p, 2);
            p += __shfl_xor(p, 4);
            p += __shfl_xor(p, 8);
            if (lq == 0) sm_part[wn][mf * 16 + lh * 4 + reg] = p;
        }
    }
    __syncthreads();
    if (tid < BM) {
        float s = 0.f;
#pragma unroll
        for (int w = 0; w < 8; ++w) s += sm_part[w][tid];
        scores[(size_t)b * S_ + m0 + tid] = s;
    }
}

// ---------------------------------------------------------------------------
// Kernel 4: in-place softmax over S per batch. grid (32), block (512), 8/thread
// ---------------------------------------------------------------------------
__global__ __launch_bounds__(512) void k_softmax(float* __restrict__ wts) {
    __shared__ float red[8];
    int b = blockIdx.x, tid = threadIdx.x;
    float* row = wts + (size_t)b * S_;
    float v[8];
    float m = -1e30f;
#pragma unroll
    for (int i = 0; i < 8; ++i) {
        v[i] = row[tid + i * 512];
        m = fmaxf(m, v[i]);
    }
#pragma unroll
    for (int o = 1; o < 64; o <<= 1) m = fmaxf(m, __shfl_xor(m, o));
    if ((tid & 63) == 0) red[tid >> 6] = m;
    __syncthreads();
    m = red[0];
#pragma unroll
    for (int w = 1; w < 8; ++w) m = fmaxf(m, red[w]);
    float sum = 0.f;
#pragma unroll
    for (int i = 0; i < 8; ++i) {
        v[i] = __expf(v[i] - m);
        sum += v[i];
    }
#pragma unroll
    for (int o = 1; o < 64; o <<= 1) sum += __shfl_xor(sum, o);
    __syncthreads();
    if ((tid & 63) == 0) red[tid >> 6] = sum;
    __syncthreads();
    float tot = 0.f;
#pragma unroll
    for (int w = 0; w < 8; ++w) tot += red[w];
    float inv = 1.f / tot;
#pragma unroll
    for (int i = 0; i < 8; ++i) row[tid + i * 512] = v[i] * inv;
}

// ---------------------------------------------------------------------------
// Kernel 5: partial context over 256-row chunks. grid (16,32), block (512)
// ---------------------------------------------------------------------------
__global__ __launch_bounds__(512) void k_ctx_part(const float* __restrict__ keys,
                                                  const float* __restrict__ wts,
                                                  float* __restrict__ part) {
    int c = blockIdx.x, b = blockIdx.y, h = threadIdx.x;
    const float* wrow = wts + (size_t)b * S_ + c * 256;
    const float* kbase = keys + ((size_t)b * S_ + c * 256) * H_ + h;
    float acc = 0.f;
#pragma unroll 8
    for (int s = 0; s < 256; ++s)
        acc = fmaf(wrow[s], kbase[(size_t)s * H_], acc);
    part[((size_t)c * B_ + b) * H_ + h] = acc;
}

// ---------------------------------------------------------------------------
// Kernel 6: reduce partials -> context. grid (32), block (512)
// ---------------------------------------------------------------------------
__global__ __launch_bounds__(512) void k_ctx_reduce(const float* __restrict__ part,
                                                    float* __restrict__ ctx) {
    int b = blockIdx.x, h = threadIdx.x;
    float s = 0.f;
#pragma unroll
    for (int c = 0; c < 16; ++c) s += part[((size_t)c * B_ + b) * H_ + h];
    ctx[(size_t)b * H_ + h] = s;
}

// ---------------------------------------------------------------------------
extern "C" void kernel_launch(void* const* d_in, const int* in_sizes, int n_in,
                              void* d_out, int out_size, void* d_ws, size_t ws_size,
                              hipStream_t stream) {
    const float* query = (const float*)d_in[0];
    const float* keys  = (const float*)d_in[1];
    const float* Wa    = (const float*)d_in[2];
    const float* Ua    = (const float*)d_in[3];
    const float* Va    = (const float*)d_in[4];

    float* out = (float*)d_out;
    float* ctx = out;             // [32,512]
    float* wts = out + B_ * H_;   // [32,4096] — raw scores written here, softmaxed in place

    char* ws = (char*)d_ws;
    unsigned short* ua_tiled = (unsigned short*)ws;               // 512 KB
    float* qproj = (float*)(ws + 524288);                         // 64 KB
    float* part  = (float*)(ws + 524288 + 65536);                 // 1 MB

    k_prep_ua<<<dim3(16, 16), dim3(32, 8), 0, stream>>>(Ua, ua_tiled);
    k_qproj<<<dim3(32), dim3(512), 0, stream>>>(query, Wa, qproj);
    k_scores<<<dim3(64, 32), dim3(512), 0, stream>>>(keys, ua_tiled, qproj, Va, wts);
    k_softmax<<<dim3(32), dim3(512), 0, stream>>>(wts);
    k_ctx_part<<<dim3(16, 32), dim3(512), 0, stream>>>(keys, wts, part);
    k_ctx_reduce<<<dim3(32), dim3(512), 0, stream>>>(part, ctx);
}